// Round 1
// baseline (1801.439 us; speedup 1.0000x reference)
//
#include <hip/hip_runtime.h>
#include <hip/hip_bf16.h>
#include <stdint.h>

#define NE 8
#define HID 512
#define OBS 32
#define ACT 16
#define DIN 48
#define DINP 64     // padded input dim
#define BTOT 32768
#define TM 64       // rows per block
#define NH 80       // padded head outputs (66 -> 80)

typedef short bf16x8 __attribute__((ext_vector_type(8)));
typedef float f32x4 __attribute__((ext_vector_type(4)));

__device__ __forceinline__ unsigned short f2bf(float f) {
    union { float f; unsigned u; } v; v.f = f;
    unsigned u = v.u + 0x7FFF + ((v.u >> 16) & 1);
    return (unsigned short)(u >> 16);
}

// ---------------- prep kernels ----------------

// X[b][c] = normalized concat(states, actions), zero-padded to 64, bf16
__global__ void prep_x(const float* __restrict__ st, const float* __restrict__ ac,
                       const float* __restrict__ sm, const float* __restrict__ ss,
                       const float* __restrict__ am, const float* __restrict__ as_,
                       unsigned short* __restrict__ X) {
    int idx = blockIdx.x * 256 + threadIdx.x;   // B*64 total
    int b = idx >> 6, c = idx & 63;
    float v = 0.f;
    if (c < OBS) v = (st[b * OBS + c] - sm[c]) / ss[c];
    else if (c < DIN) { int ca = c - OBS; v = (ac[b * ACT + ca] - am[ca]) / as_[ca]; }
    X[idx] = f2bf(v);
}

// T1[e][n][k] = W1[e][k][n] (k<48 else 0), bf16, K padded to 64
__global__ void prep_w1(const float* __restrict__ W1, unsigned short* __restrict__ T1) {
    int idx = blockIdx.x * 256 + threadIdx.x;   // 8*512*64
    int k = idx & 63, n = (idx >> 6) & 511, e = idx >> 15;
    float v = (k < DIN) ? W1[((size_t)e * DIN + k) * HID + n] : 0.f;
    T1[idx] = f2bf(v);
}

// Transposed bf16 copies of W2/W3/W4: T[z][n][k] = Wsrc[e][k][n], z = l*8+e
__global__ void prep_wh(const float* __restrict__ W2, const float* __restrict__ W3,
                        const float* __restrict__ W4, unsigned short* __restrict__ T) {
    __shared__ float tile[32][33];
    int z = blockIdx.z;
    const float* src = (z < 8 ? W2 : (z < 16 ? W3 : W4)) + (size_t)(z & 7) * HID * HID;
    unsigned short* dst = T + (size_t)z * HID * HID;
    int n0 = blockIdx.x * 32, k0 = blockIdx.y * 32;
    int tx = threadIdx.x, ty = threadIdx.y;     // 32 x 8
    #pragma unroll
    for (int i = 0; i < 32; i += 8)
        tile[ty + i][tx] = src[(size_t)(k0 + ty + i) * HID + n0 + tx];
    __syncthreads();
    #pragma unroll
    for (int i = 0; i < 32; i += 8)
        dst[(size_t)(n0 + ty + i) * HID + k0 + tx] = f2bf(tile[tx][ty + i]);
}

// Fused head weights TH[e][n][k] (n<32 means, <64 logstd, 64 reward, 65 done, rest 0)
// and fused head bias BH[e][n]
__global__ void prep_head(const float* __restrict__ Wm, const float* __restrict__ Wls,
                          const float* __restrict__ Wr, const float* __restrict__ Wd,
                          const float* __restrict__ bm, const float* __restrict__ bls,
                          const float* __restrict__ br, const float* __restrict__ bd,
                          unsigned short* __restrict__ TH, float* __restrict__ BH) {
    int idx = blockIdx.x * 256 + threadIdx.x;   // 8*80*512
    if (idx < NE * NH * HID) {
        int k = idx & 511, n = (idx >> 9) % NH, e = idx / (NH * HID);
        float v = 0.f;
        if (n < 32)       v = Wm [((size_t)e * HID + k) * OBS + n];
        else if (n < 64)  v = Wls[((size_t)e * HID + k) * OBS + (n - 32)];
        else if (n == 64) v = Wr [(size_t)e * HID + k];
        else if (n == 65) v = Wd [(size_t)e * HID + k];
        TH[idx] = f2bf(v);
    }
    if (idx < NE * NH) {
        int n = idx % NH, e = idx / NH;
        float v = 0.f;
        if (n < 32)       v = bm [e * OBS + n];
        else if (n < 64)  v = bls[e * OBS + (n - 32)];
        else if (n == 64) v = br [e];
        else if (n == 65) v = bd [e];
        BH[idx] = v;
    }
}

// ---------------- main fused kernel ----------------

__device__ __forceinline__ bf16x8 load_a(const unsigned short* hb, int row, int k) {
    int off = row * 1024 + ((k * 2) ^ ((row & 7) << 4));
    return *(const bf16x8*)((const char*)hb + off);
}

template<int KD, bool RELU>
__device__ __forceinline__ void mlp_layer(const unsigned short* __restrict__ Tw,
                                          const float* __restrict__ bias,
                                          unsigned short* hb,
                                          int lane, int wr, int wc) {
    const int l15 = lane & 15, lk = (lane >> 4) * 8;
    f32x4 acc[2][8];
    #pragma unroll
    for (int ct = 0; ct < 8; ++ct) {
        float bv = bias[wc * 128 + ct * 16 + l15];
        f32x4 b4 = {bv, bv, bv, bv};
        acc[0][ct] = b4; acc[1][ct] = b4;
    }
    const int r0 = wr * 32 + l15, r1 = r0 + 16;
    #pragma unroll
    for (int ks = 0; ks < KD / 32; ++ks) {
        int k = ks * 32 + lk;
        bf16x8 a0 = load_a(hb, r0, k);
        bf16x8 a1 = load_a(hb, r1, k);
        #pragma unroll
        for (int ct = 0; ct < 8; ++ct) {
            bf16x8 bf = *(const bf16x8*)(Tw + (size_t)(wc * 128 + ct * 16 + l15) * KD + k);
            acc[0][ct] = __builtin_amdgcn_mfma_f32_16x16x32_bf16(a0, bf, acc[0][ct], 0, 0, 0);
            acc[1][ct] = __builtin_amdgcn_mfma_f32_16x16x32_bf16(a1, bf, acc[1][ct], 0, 0, 0);
        }
    }
    __syncthreads();
    #pragma unroll
    for (int rt = 0; rt < 2; ++rt)
        #pragma unroll
        for (int ct = 0; ct < 8; ++ct)
            #pragma unroll
            for (int j = 0; j < 4; ++j) {
                int row = wr * 32 + rt * 16 + (lane >> 4) * 4 + j;
                int col = wc * 128 + ct * 16 + l15;
                float v = acc[rt][ct][j];
                if (RELU) v = fmaxf(v, 0.f);
                *(unsigned short*)((char*)hb + row * 1024 + ((col * 2) ^ ((row & 7) << 4))) = f2bf(v);
            }
    __syncthreads();
}

__launch_bounds__(512, 2)
__global__ void ens_mlp(const unsigned short* __restrict__ X,
                        const unsigned short* __restrict__ T1, const unsigned short* __restrict__ T2,
                        const unsigned short* __restrict__ T3, const unsigned short* __restrict__ T4,
                        const unsigned short* __restrict__ TH,
                        const float* __restrict__ b1, const float* __restrict__ b2,
                        const float* __restrict__ b3, const float* __restrict__ b4,
                        const float* __restrict__ BH,
                        const float* __restrict__ dmean, const float* __restrict__ dstd,
                        float* __restrict__ out) {
    __shared__ unsigned short hbuf[TM * HID];   // 64 KB, XOR-swizzled rows
    const int bid = blockIdx.x;
    const int e = bid & 7;                      // ensemble -> XCD affinity
    const int tile = bid >> 3;
    const int row0 = tile * TM;
    const int tid = threadIdx.x, lane = tid & 63, wid = tid >> 6;
    const int wr = wid & 1, wc = wid >> 1;

    // stage X tile (64 rows x 64 bf16), swizzled
    {
        int r = tid >> 3, c = tid & 7;          // 16B chunk index
        int4 v = *(const int4*)(X + (size_t)(row0 + r) * DINP + c * 8);
        *(int4*)((char*)hbuf + r * 1024 + ((c ^ (r & 7)) << 4)) = v;
    }
    __syncthreads();

    mlp_layer<64,  true>(T1 + (size_t)e * HID * 64,  b1 + e * HID, hbuf, lane, wr, wc);
    mlp_layer<512, true>(T2 + (size_t)e * HID * HID, b2 + e * HID, hbuf, lane, wr, wc);
    mlp_layer<512, true>(T3 + (size_t)e * HID * HID, b3 + e * HID, hbuf, lane, wr, wc);
    mlp_layer<512, true>(T4 + (size_t)e * HID * HID, b4 + e * HID, hbuf, lane, wr, wc);

    // ---- heads: 20 tile-jobs (rt 0..3, ct 0..4) over 8 waves ----
    const int l15 = lane & 15, lk = (lane >> 4) * 8;
    const int j0 = wid, j1 = wid + 8, j2 = wid + 16;
    const bool has2 = (j2 < 20);
    const int rt0 = j0 / 5, ct0 = j0 % 5;
    const int rt1 = j1 / 5, ct1 = j1 % 5;
    const int rt2 = has2 ? j2 / 5 : 0, ct2 = has2 ? j2 % 5 : 0;
    const unsigned short* THe = TH + (size_t)e * NH * HID;
    const float* BHe = BH + e * NH;

    f32x4 h0, h1, h2;
    { float bv = BHe[ct0 * 16 + l15]; h0 = (f32x4){bv, bv, bv, bv}; }
    { float bv = BHe[ct1 * 16 + l15]; h1 = (f32x4){bv, bv, bv, bv}; }
    { float bv = BHe[ct2 * 16 + l15]; h2 = (f32x4){bv, bv, bv, bv}; }

    #pragma unroll
    for (int ks = 0; ks < 16; ++ks) {
        int k = ks * 32 + lk;
        bf16x8 a0 = load_a(hbuf, rt0 * 16 + l15, k);
        bf16x8 w0 = *(const bf16x8*)(THe + (size_t)(ct0 * 16 + l15) * HID + k);
        h0 = __builtin_amdgcn_mfma_f32_16x16x32_bf16(a0, w0, h0, 0, 0, 0);
        bf16x8 a1 = load_a(hbuf, rt1 * 16 + l15, k);
        bf16x8 w1 = *(const bf16x8*)(THe + (size_t)(ct1 * 16 + l15) * HID + k);
        h1 = __builtin_amdgcn_mfma_f32_16x16x32_bf16(a1, w1, h1, 0, 0, 0);
        if (has2) {
            bf16x8 a2 = load_a(hbuf, rt2 * 16 + l15, k);
            bf16x8 w2 = *(const bf16x8*)(THe + (size_t)(ct2 * 16 + l15) * HID + k);
            h2 = __builtin_amdgcn_mfma_f32_16x16x32_bf16(a2, w2, h2, 0, 0, 0);
        }
    }

    // ---- epilogue: clip/exp/denorm, write concatenated fp32 outputs ----
    const size_t STDS_OFF = (size_t)NE * BTOT * OBS;
    const size_t REW_OFF  = 2 * STDS_OFF;
    const size_t DONE_OFF = REW_OFF + (size_t)NE * BTOT;

    auto emit = [&](int rt, int ct, f32x4 v) {
        int col = ct * 16 + l15;
        #pragma unroll
        for (int j = 0; j < 4; ++j) {
            int row = row0 + rt * 16 + (lane >> 4) * 4 + j;
            size_t rb = (size_t)e * BTOT + row;
            float x = v[j];
            if (col < 32) {
                out[rb * 32 + col] = x * dstd[col] + dmean[col];
            } else if (col < 64) {
                int c = col - 32;
                float ls = fminf(fmaxf(x, -10.f), 0.5f);
                out[STDS_OFF + rb * 32 + c] = expf(ls) * dstd[c];
            } else if (col == 64) {
                out[REW_OFF + rb] = x;
            } else if (col == 65) {
                out[DONE_OFF + rb] = x;
            }
        }
    };
    emit(rt0, ct0, h0);
    emit(rt1, ct1, h1);
    if (has2) emit(rt2, ct2, h2);
}

// ---------------- launch ----------------

extern "C" void kernel_launch(void* const* d_in, const int* in_sizes, int n_in,
                              void* d_out, int out_size, void* d_ws, size_t ws_size,
                              hipStream_t stream) {
    const float* states  = (const float*)d_in[0];
    const float* actions = (const float*)d_in[1];
    const float* smean   = (const float*)d_in[2];
    const float* sstd    = (const float*)d_in[3];
    const float* amean   = (const float*)d_in[4];
    const float* astd    = (const float*)d_in[5];
    const float* dmean   = (const float*)d_in[6];
    const float* dstd    = (const float*)d_in[7];
    const float* W1 = (const float*)d_in[8];
    const float* b1 = (const float*)d_in[9];
    const float* W2 = (const float*)d_in[10];
    const float* b2 = (const float*)d_in[11];
    const float* W3 = (const float*)d_in[12];
    const float* b3 = (const float*)d_in[13];
    const float* W4 = (const float*)d_in[14];
    const float* b4 = (const float*)d_in[15];
    const float* Wm = (const float*)d_in[16];
    const float* bm = (const float*)d_in[17];
    const float* Wls = (const float*)d_in[18];
    const float* bls = (const float*)d_in[19];
    const float* Wr = (const float*)d_in[20];
    const float* br = (const float*)d_in[21];
    const float* Wd = (const float*)d_in[22];
    const float* bd = (const float*)d_in[23];

    char* ws = (char*)d_ws;
    unsigned short* X  = (unsigned short*)(ws);                 // 4,194,304 B
    unsigned short* T1 = (unsigned short*)(ws + 4194304);       //   524,288 B
    unsigned short* T2 = (unsigned short*)(ws + 4718592);       // 4,194,304 B
    unsigned short* T3 = (unsigned short*)(ws + 8912896);
    unsigned short* T4 = (unsigned short*)(ws + 13107200);
    unsigned short* TH = (unsigned short*)(ws + 17301504);      //   655,360 B
    float*          BH = (float*)(ws + 17956864);               //     2,560 B

    prep_x<<<(BTOT * 64) / 256, 256, 0, stream>>>(states, actions, smean, sstd, amean, astd, X);
    prep_w1<<<(NE * HID * 64) / 256, 256, 0, stream>>>(W1, T1);
    dim3 gT(16, 16, 24), bT(32, 8);
    prep_wh<<<gT, bT, 0, stream>>>(W2, W3, W4, T2);
    prep_head<<<(NE * NH * HID) / 256, 256, 0, stream>>>(Wm, Wls, Wr, Wd, bm, bls, br, bd, TH, BH);

    ens_mlp<<<NE * (BTOT / TM), 512, 0, stream>>>(X, T1, T2, T3, T4, TH,
                                                  b1, b2, b3, b4, BH, dmean, dstd,
                                                  (float*)d_out);
}

// Round 3
// 1326.291 us; speedup vs baseline: 1.3583x; 1.3583x over previous
//
#include <hip/hip_runtime.h>
#include <hip/hip_bf16.h>
#include <stdint.h>

#define NE 8
#define HID 512
#define OBS 32
#define ACT 16
#define DIN 48
#define DINP 64     // padded input dim
#define BTOT 32768
#define TM 64       // rows per block
#define NH 80       // padded head outputs (66 -> 80)

typedef short bf16x8 __attribute__((ext_vector_type(8)));
typedef float f32x4 __attribute__((ext_vector_type(4)));

__device__ __forceinline__ unsigned short f2bf(float f) {
    union { float f; unsigned u; } v; v.f = f;
    unsigned u = v.u + 0x7FFF + ((v.u >> 16) & 1);
    return (unsigned short)(u >> 16);
}

// ---------------- prep kernels ----------------

// X[b][c] = normalized concat(states, actions), zero-padded to 64, bf16
__global__ void prep_x(const float* __restrict__ st, const float* __restrict__ ac,
                       const float* __restrict__ sm, const float* __restrict__ ss,
                       const float* __restrict__ am, const float* __restrict__ as_,
                       unsigned short* __restrict__ X) {
    int idx = blockIdx.x * 256 + threadIdx.x;   // B*64 total
    int b = idx >> 6, c = idx & 63;
    float v = 0.f;
    if (c < OBS) v = (st[b * OBS + c] - sm[c]) / ss[c];
    else if (c < DIN) { int ca = c - OBS; v = (ac[b * ACT + ca] - am[ca]) / as_[ca]; }
    X[idx] = f2bf(v);
}

// T1[e][n][k] = W1[e][k][n] (k<48 else 0), bf16, K padded to 64
__global__ void prep_w1(const float* __restrict__ W1, unsigned short* __restrict__ T1) {
    int idx = blockIdx.x * 256 + threadIdx.x;   // 8*512*64
    int k = idx & 63, n = (idx >> 6) & 511, e = idx >> 15;
    float v = (k < DIN) ? W1[((size_t)e * DIN + k) * HID + n] : 0.f;
    T1[idx] = f2bf(v);
}

// Transposed bf16 copies of W2/W3/W4: T[z][n][k] = Wsrc[e][k][n], z = l*8+e
__global__ void prep_wh(const float* __restrict__ W2, const float* __restrict__ W3,
                        const float* __restrict__ W4, unsigned short* __restrict__ T) {
    __shared__ float tile[32][33];
    int z = blockIdx.z;
    const float* src = (z < 8 ? W2 : (z < 16 ? W3 : W4)) + (size_t)(z & 7) * HID * HID;
    unsigned short* dst = T + (size_t)z * HID * HID;
    int n0 = blockIdx.x * 32, k0 = blockIdx.y * 32;
    int tx = threadIdx.x, ty = threadIdx.y;     // 32 x 8
    #pragma unroll
    for (int i = 0; i < 32; i += 8)
        tile[ty + i][tx] = src[(size_t)(k0 + ty + i) * HID + n0 + tx];
    __syncthreads();
    #pragma unroll
    for (int i = 0; i < 32; i += 8)
        dst[(size_t)(n0 + ty + i) * HID + k0 + tx] = f2bf(tile[tx][ty + i]);
}

// Fused head weights TH[e][n][k] (n<32 means, <64 logstd, 64 reward, 65 done, rest 0)
// and fused head bias BH[e][n]
__global__ void prep_head(const float* __restrict__ Wm, const float* __restrict__ Wls,
                          const float* __restrict__ Wr, const float* __restrict__ Wd,
                          const float* __restrict__ bm, const float* __restrict__ bls,
                          const float* __restrict__ br, const float* __restrict__ bd,
                          unsigned short* __restrict__ TH, float* __restrict__ BH) {
    int idx = blockIdx.x * 256 + threadIdx.x;   // 8*80*512
    if (idx < NE * NH * HID) {
        int k = idx & 511, n = (idx >> 9) % NH, e = idx / (NH * HID);
        float v = 0.f;
        if (n < 32)       v = Wm [((size_t)e * HID + k) * OBS + n];
        else if (n < 64)  v = Wls[((size_t)e * HID + k) * OBS + (n - 32)];
        else if (n == 64) v = Wr [(size_t)e * HID + k];
        else if (n == 65) v = Wd [(size_t)e * HID + k];
        TH[idx] = f2bf(v);
    }
    if (idx < NE * NH) {
        int n = idx % NH, e = idx / NH;
        float v = 0.f;
        if (n < 32)       v = bm [e * OBS + n];
        else if (n < 64)  v = bls[e * OBS + (n - 32)];
        else if (n == 64) v = br [e];
        else if (n == 65) v = bd [e];
        BH[idx] = v;
    }
}

// ---------------- main fused kernel ----------------

__device__ __forceinline__ bf16x8 load_a(const unsigned short* hb, int row, int k) {
    int off = row * 1024 + ((k * 2) ^ ((row & 7) << 4));
    return *(const bf16x8*)((const char*)hb + off);
}

// Each wave owns ALL 64 rows x 64 cols (cols = wid*64 .. +63).
// 4 B-frag loads per 16 MFMAs, no intra-block B redundancy, next-ks register
// double buffer keeps weight loads in flight under the MFMA cluster.
template<int KD, bool RELU>
__device__ __forceinline__ void mlp_layer(const unsigned short* __restrict__ Tw,
                                          const float* __restrict__ bias,
                                          unsigned short* hb,
                                          int lane, int wid) {
    const int l15 = lane & 15, lk = (lane >> 4) * 8;
    const int col0 = wid * 64;
    constexpr int NK = KD / 32;

    f32x4 acc[4][4];
    #pragma unroll
    for (int ct = 0; ct < 4; ++ct) {
        float bv = bias[col0 + ct * 16 + l15];
        f32x4 b4 = {bv, bv, bv, bv};
        #pragma unroll
        for (int rt = 0; rt < 4; ++rt) acc[rt][ct] = b4;
    }

    // B row base for this lane: row (col0 + ct*16 + l15), k = ks*32 + lk
    const unsigned short* Bb = Tw + (size_t)(col0 + l15) * KD + lk;

    bf16x8 bcur[4], bnxt[4];
    #pragma unroll
    for (int ct = 0; ct < 4; ++ct)
        bcur[ct] = *(const bf16x8*)(Bb + ct * 16 * KD);

    #pragma unroll
    for (int ks = 0; ks < NK; ++ks) {
        const int k = ks * 32 + lk;
        if (ks + 1 < NK) {
            #pragma unroll
            for (int ct = 0; ct < 4; ++ct)
                bnxt[ct] = *(const bf16x8*)(Bb + ct * 16 * KD + (ks + 1) * 32);
        }
        bf16x8 a0 = load_a(hb, 0 * 16 + l15, k);
        bf16x8 a1 = load_a(hb, 1 * 16 + l15, k);
        #pragma unroll
        for (int ct = 0; ct < 4; ++ct) {
            acc[0][ct] = __builtin_amdgcn_mfma_f32_16x16x32_bf16(a0, bcur[ct], acc[0][ct], 0, 0, 0);
            acc[1][ct] = __builtin_amdgcn_mfma_f32_16x16x32_bf16(a1, bcur[ct], acc[1][ct], 0, 0, 0);
        }
        bf16x8 a2 = load_a(hb, 2 * 16 + l15, k);
        bf16x8 a3 = load_a(hb, 3 * 16 + l15, k);
        #pragma unroll
        for (int ct = 0; ct < 4; ++ct) {
            acc[2][ct] = __builtin_amdgcn_mfma_f32_16x16x32_bf16(a2, bcur[ct], acc[2][ct], 0, 0, 0);
            acc[3][ct] = __builtin_amdgcn_mfma_f32_16x16x32_bf16(a3, bcur[ct], acc[3][ct], 0, 0, 0);
        }
        if (ks + 1 < NK) {
            #pragma unroll
            for (int ct = 0; ct < 4; ++ct) bcur[ct] = bnxt[ct];
        }
    }
    __syncthreads();
    #pragma unroll
    for (int rt = 0; rt < 4; ++rt)
        #pragma unroll
        for (int ct = 0; ct < 4; ++ct)
            #pragma unroll
            for (int j = 0; j < 4; ++j) {
                int row = rt * 16 + (lane >> 4) * 4 + j;
                int col = col0 + ct * 16 + l15;
                float v = acc[rt][ct][j];
                if (RELU) v = fmaxf(v, 0.f);
                *(unsigned short*)((char*)hb + row * 1024 + ((col * 2) ^ ((row & 7) << 4))) = f2bf(v);
            }
    __syncthreads();
}

__launch_bounds__(512, 4)
__global__ void ens_mlp(const unsigned short* __restrict__ X,
                        const unsigned short* __restrict__ T1, const unsigned short* __restrict__ T2,
                        const unsigned short* __restrict__ T3, const unsigned short* __restrict__ T4,
                        const unsigned short* __restrict__ TH,
                        const float* __restrict__ b1, const float* __restrict__ b2,
                        const float* __restrict__ b3, const float* __restrict__ b4,
                        const float* __restrict__ BH,
                        const float* __restrict__ dmean, const float* __restrict__ dstd,
                        float* __restrict__ out) {
    __shared__ unsigned short hbuf[TM * HID];   // 64 KB, XOR-swizzled rows
    const int bid = blockIdx.x;
    const int e = bid & 7;                      // ensemble -> XCD affinity
    const int tile = bid >> 3;
    const int row0 = tile * TM;
    const int tid = threadIdx.x, lane = tid & 63, wid = tid >> 6;

    // stage X tile (64 rows x 64 bf16), swizzled
    {
        int r = tid >> 3, c = tid & 7;          // 16B chunk index
        int4 v = *(const int4*)(X + (size_t)(row0 + r) * DINP + c * 8);
        *(int4*)((char*)hbuf + r * 1024 + ((c ^ (r & 7)) << 4)) = v;
    }
    __syncthreads();

    mlp_layer<64,  true>(T1 + (size_t)e * HID * 64,  b1 + e * HID, hbuf, lane, wid);
    mlp_layer<512, true>(T2 + (size_t)e * HID * HID, b2 + e * HID, hbuf, lane, wid);
    mlp_layer<512, true>(T3 + (size_t)e * HID * HID, b3 + e * HID, hbuf, lane, wid);
    mlp_layer<512, true>(T4 + (size_t)e * HID * HID, b4 + e * HID, hbuf, lane, wid);

    // ---- heads: 20 tile-jobs (rt 0..3, ct 0..4) over 8 waves ----
    const int l15 = lane & 15, lk = (lane >> 4) * 8;
    const int j0 = wid, j1 = wid + 8, j2 = wid + 16;
    const bool has2 = (j2 < 20);
    const int rt0 = j0 / 5, ct0 = j0 % 5;
    const int rt1 = j1 / 5, ct1 = j1 % 5;
    const int rt2 = has2 ? j2 / 5 : 0, ct2 = has2 ? j2 % 5 : 0;
    const unsigned short* THe = TH + (size_t)e * NH * HID;
    const float* BHe = BH + e * NH;

    f32x4 h0, h1, h2;
    { float bv = BHe[ct0 * 16 + l15]; h0 = (f32x4){bv, bv, bv, bv}; }
    { float bv = BHe[ct1 * 16 + l15]; h1 = (f32x4){bv, bv, bv, bv}; }
    { float bv = BHe[ct2 * 16 + l15]; h2 = (f32x4){bv, bv, bv, bv}; }

    #pragma unroll
    for (int ks = 0; ks < 16; ++ks) {
        int k = ks * 32 + lk;
        bf16x8 a0 = load_a(hbuf, rt0 * 16 + l15, k);
        bf16x8 w0 = *(const bf16x8*)(THe + (size_t)(ct0 * 16 + l15) * HID + k);
        h0 = __builtin_amdgcn_mfma_f32_16x16x32_bf16(a0, w0, h0, 0, 0, 0);
        bf16x8 a1 = load_a(hbuf, rt1 * 16 + l15, k);
        bf16x8 w1 = *(const bf16x8*)(THe + (size_t)(ct1 * 16 + l15) * HID + k);
        h1 = __builtin_amdgcn_mfma_f32_16x16x32_bf16(a1, w1, h1, 0, 0, 0);
        if (has2) {
            bf16x8 a2 = load_a(hbuf, rt2 * 16 + l15, k);
            bf16x8 w2 = *(const bf16x8*)(THe + (size_t)(ct2 * 16 + l15) * HID + k);
            h2 = __builtin_amdgcn_mfma_f32_16x16x32_bf16(a2, w2, h2, 0, 0, 0);
        }
    }

    // ---- epilogue: clip/exp/denorm, write concatenated fp32 outputs ----
    const size_t STDS_OFF = (size_t)NE * BTOT * OBS;
    const size_t REW_OFF  = 2 * STDS_OFF;
    const size_t DONE_OFF = REW_OFF + (size_t)NE * BTOT;

    auto emit = [&](int rt, int ct, f32x4 v) {
        int col = ct * 16 + l15;
        #pragma unroll
        for (int j = 0; j < 4; ++j) {
            int row = row0 + rt * 16 + (lane >> 4) * 4 + j;
            size_t rb = (size_t)e * BTOT + row;
            float x = v[j];
            if (col < 32) {
                out[rb * 32 + col] = x * dstd[col] + dmean[col];
            } else if (col < 64) {
                int c = col - 32;
                float ls = fminf(fmaxf(x, -10.f), 0.5f);
                out[STDS_OFF + rb * 32 + c] = expf(ls) * dstd[c];
            } else if (col == 64) {
                out[REW_OFF + rb] = x;
            } else if (col == 65) {
                out[DONE_OFF + rb] = x;
            }
        }
    };
    emit(rt0, ct0, h0);
    emit(rt1, ct1, h1);
    if (has2) emit(rt2, ct2, h2);
}

// ---------------- launch ----------------

extern "C" void kernel_launch(void* const* d_in, const int* in_sizes, int n_in,
                              void* d_out, int out_size, void* d_ws, size_t ws_size,
                              hipStream_t stream) {
    const float* states  = (const float*)d_in[0];
    const float* actions = (const float*)d_in[1];
    const float* smean   = (const float*)d_in[2];
    const float* sstd    = (const float*)d_in[3];
    const float* amean   = (const float*)d_in[4];
    const float* astd    = (const float*)d_in[5];
    const float* dmean   = (const float*)d_in[6];
    const float* dstd    = (const float*)d_in[7];
    const float* W1 = (const float*)d_in[8];
    const float* b1 = (const float*)d_in[9];
    const float* W2 = (const float*)d_in[10];
    const float* b2 = (const float*)d_in[11];
    const float* W3 = (const float*)d_in[12];
    const float* b3 = (const float*)d_in[13];
    const float* W4 = (const float*)d_in[14];
    const float* b4 = (const float*)d_in[15];
    const float* Wm = (const float*)d_in[16];
    const float* bm = (const float*)d_in[17];
    const float* Wls = (const float*)d_in[18];
    const float* bls = (const float*)d_in[19];
    const float* Wr = (const float*)d_in[20];
    const float* br = (const float*)d_in[21];
    const float* Wd = (const float*)d_in[22];
    const float* bd = (const float*)d_in[23];

    char* ws = (char*)d_ws;
    unsigned short* X  = (unsigned short*)(ws);                 // 4,194,304 B
    unsigned short* T1 = (unsigned short*)(ws + 4194304);       //   524,288 B
    unsigned short* T2 = (unsigned short*)(ws + 4718592);       // 4,194,304 B
    unsigned short* T3 = (unsigned short*)(ws + 8912896);
    unsigned short* T4 = (unsigned short*)(ws + 13107200);
    unsigned short* TH = (unsigned short*)(ws + 17301504);      //   655,360 B
    float*          BH = (float*)(ws + 17956864);               //     2,560 B

    prep_x<<<(BTOT * 64) / 256, 256, 0, stream>>>(states, actions, smean, sstd, amean, astd, X);
    prep_w1<<<(NE * HID * 64) / 256, 256, 0, stream>>>(W1, T1);
    dim3 gT(16, 16, 24), bT(32, 8);
    prep_wh<<<gT, bT, 0, stream>>>(W2, W3, W4, T2);
    prep_head<<<(NE * NH * HID) / 256, 256, 0, stream>>>(Wm, Wls, Wr, Wd, bm, bls, br, bd, TH, BH);

    ens_mlp<<<NE * (BTOT / TM), 512, 0, stream>>>(X, T1, T2, T3, T4, TH,
                                                  b1, b2, b3, b4, BH, dmean, dstd,
                                                  (float*)d_out);
}

// Round 4
// 1122.639 us; speedup vs baseline: 1.6046x; 1.1814x over previous
//
#include <hip/hip_runtime.h>
#include <hip/hip_bf16.h>
#include <stdint.h>

#define NE 8
#define HID 512
#define OBS 32
#define ACT 16
#define DIN 48
#define DINP 64     // padded input dim
#define BTOT 32768
#define TM 64       // rows per block
#define NH 80       // padded head outputs (66 -> 80)

typedef short bf16x8 __attribute__((ext_vector_type(8)));
typedef float f32x4 __attribute__((ext_vector_type(4)));

__device__ __forceinline__ unsigned short f2bf(float f) {
    union { float f; unsigned u; } v; v.f = f;
    unsigned u = v.u + 0x7FFF + ((v.u >> 16) & 1);
    return (unsigned short)(u >> 16);
}

// ---------------- prep kernels ----------------

// X[b][c] = normalized concat(states, actions), zero-padded to 64, bf16
__global__ void prep_x(const float* __restrict__ st, const float* __restrict__ ac,
                       const float* __restrict__ sm, const float* __restrict__ ss,
                       const float* __restrict__ am, const float* __restrict__ as_,
                       unsigned short* __restrict__ X) {
    int idx = blockIdx.x * 256 + threadIdx.x;   // B*64 total
    int b = idx >> 6, c = idx & 63;
    float v = 0.f;
    if (c < OBS) v = (st[b * OBS + c] - sm[c]) / ss[c];
    else if (c < DIN) { int ca = c - OBS; v = (ac[b * ACT + ca] - am[ca]) / as_[ca]; }
    X[idx] = f2bf(v);
}

// T1[e][n][k] = W1[e][k][n] (k<48 else 0), bf16, K padded to 64
__global__ void prep_w1(const float* __restrict__ W1, unsigned short* __restrict__ T1) {
    int idx = blockIdx.x * 256 + threadIdx.x;   // 8*512*64
    int k = idx & 63, n = (idx >> 6) & 511, e = idx >> 15;
    float v = (k < DIN) ? W1[((size_t)e * DIN + k) * HID + n] : 0.f;
    T1[idx] = f2bf(v);
}

// Transposed bf16 copies of W2/W3/W4: T[z][n][k] = Wsrc[e][k][n], z = l*8+e
__global__ void prep_wh(const float* __restrict__ W2, const float* __restrict__ W3,
                        const float* __restrict__ W4, unsigned short* __restrict__ T) {
    __shared__ float tile[32][33];
    int z = blockIdx.z;
    const float* src = (z < 8 ? W2 : (z < 16 ? W3 : W4)) + (size_t)(z & 7) * HID * HID;
    unsigned short* dst = T + (size_t)z * HID * HID;
    int n0 = blockIdx.x * 32, k0 = blockIdx.y * 32;
    int tx = threadIdx.x, ty = threadIdx.y;     // 32 x 8
    #pragma unroll
    for (int i = 0; i < 32; i += 8)
        tile[ty + i][tx] = src[(size_t)(k0 + ty + i) * HID + n0 + tx];
    __syncthreads();
    #pragma unroll
    for (int i = 0; i < 32; i += 8)
        dst[(size_t)(n0 + ty + i) * HID + k0 + tx] = f2bf(tile[tx][ty + i]);
}

// Fused head weights TH[e][n][k] (n<32 means, <64 logstd, 64 reward, 65 done, rest 0)
// and fused head bias BH[e][n]
__global__ void prep_head(const float* __restrict__ Wm, const float* __restrict__ Wls,
                          const float* __restrict__ Wr, const float* __restrict__ Wd,
                          const float* __restrict__ bm, const float* __restrict__ bls,
                          const float* __restrict__ br, const float* __restrict__ bd,
                          unsigned short* __restrict__ TH, float* __restrict__ BH) {
    int idx = blockIdx.x * 256 + threadIdx.x;   // 8*80*512
    if (idx < NE * NH * HID) {
        int k = idx & 511, n = (idx >> 9) % NH, e = idx / (NH * HID);
        float v = 0.f;
        if (n < 32)       v = Wm [((size_t)e * HID + k) * OBS + n];
        else if (n < 64)  v = Wls[((size_t)e * HID + k) * OBS + (n - 32)];
        else if (n == 64) v = Wr [(size_t)e * HID + k];
        else if (n == 65) v = Wd [(size_t)e * HID + k];
        TH[idx] = f2bf(v);
    }
    if (idx < NE * NH) {
        int n = idx % NH, e = idx / NH;
        float v = 0.f;
        if (n < 32)       v = bm [e * OBS + n];
        else if (n < 64)  v = bls[e * OBS + (n - 32)];
        else if (n == 64) v = br [e];
        else if (n == 65) v = bd [e];
        BH[idx] = v;
    }
}

// ---------------- main fused kernel ----------------

__device__ __forceinline__ bf16x8 load_a(const unsigned short* hb, int row, int k) {
    int off = row * 1024 + ((k * 2) ^ ((row & 7) << 4));
    return *(const bf16x8*)((const char*)hb + off);
}

// Each wave owns ALL 64 rows x 64 cols (cols = wid*64 .. +63).
// 4 B-frag loads per 16 MFMAs, no intra-block B redundancy, next-ks register
// double buffer keeps weight loads in flight under the MFMA cluster.
template<int KD, bool RELU>
__device__ __forceinline__ void mlp_layer(const unsigned short* __restrict__ Tw,
                                          const float* __restrict__ bias,
                                          unsigned short* hb,
                                          int lane, int wid) {
    const int l15 = lane & 15, lk = (lane >> 4) * 8;
    const int col0 = wid * 64;
    constexpr int NK = KD / 32;

    f32x4 acc[4][4];
    #pragma unroll
    for (int ct = 0; ct < 4; ++ct) {
        float bv = bias[col0 + ct * 16 + l15];
        f32x4 b4 = {bv, bv, bv, bv};
        #pragma unroll
        for (int rt = 0; rt < 4; ++rt) acc[rt][ct] = b4;
    }

    // B row base for this lane: row (col0 + ct*16 + l15), k = ks*32 + lk
    const unsigned short* Bb = Tw + (size_t)(col0 + l15) * KD + lk;

    bf16x8 bcur[4], bnxt[4];
    #pragma unroll
    for (int ct = 0; ct < 4; ++ct)
        bcur[ct] = *(const bf16x8*)(Bb + ct * 16 * KD);

    #pragma unroll
    for (int ks = 0; ks < NK; ++ks) {
        const int k = ks * 32 + lk;
        if (ks + 1 < NK) {
            #pragma unroll
            for (int ct = 0; ct < 4; ++ct)
                bnxt[ct] = *(const bf16x8*)(Bb + ct * 16 * KD + (ks + 1) * 32);
        }
        bf16x8 a0 = load_a(hb, 0 * 16 + l15, k);
        bf16x8 a1 = load_a(hb, 1 * 16 + l15, k);
        #pragma unroll
        for (int ct = 0; ct < 4; ++ct) {
            acc[0][ct] = __builtin_amdgcn_mfma_f32_16x16x32_bf16(a0, bcur[ct], acc[0][ct], 0, 0, 0);
            acc[1][ct] = __builtin_amdgcn_mfma_f32_16x16x32_bf16(a1, bcur[ct], acc[1][ct], 0, 0, 0);
        }
        bf16x8 a2 = load_a(hb, 2 * 16 + l15, k);
        bf16x8 a3 = load_a(hb, 3 * 16 + l15, k);
        #pragma unroll
        for (int ct = 0; ct < 4; ++ct) {
            acc[2][ct] = __builtin_amdgcn_mfma_f32_16x16x32_bf16(a2, bcur[ct], acc[2][ct], 0, 0, 0);
            acc[3][ct] = __builtin_amdgcn_mfma_f32_16x16x32_bf16(a3, bcur[ct], acc[3][ct], 0, 0, 0);
        }
        if (ks + 1 < NK) {
            #pragma unroll
            for (int ct = 0; ct < 4; ++ct) bcur[ct] = bnxt[ct];
        }
    }
    __syncthreads();
    #pragma unroll
    for (int rt = 0; rt < 4; ++rt)
        #pragma unroll
        for (int ct = 0; ct < 4; ++ct)
            #pragma unroll
            for (int j = 0; j < 4; ++j) {
                int row = rt * 16 + (lane >> 4) * 4 + j;
                int col = col0 + ct * 16 + l15;
                float v = acc[rt][ct][j];
                if (RELU) v = fmaxf(v, 0.f);
                *(unsigned short*)((char*)hb + row * 1024 + ((col * 2) ^ ((row & 7) << 4))) = f2bf(v);
            }
    __syncthreads();
}

__launch_bounds__(512, 2)
__global__ void ens_mlp(const unsigned short* __restrict__ X,
                        const unsigned short* __restrict__ T1, const unsigned short* __restrict__ T2,
                        const unsigned short* __restrict__ T3, const unsigned short* __restrict__ T4,
                        const unsigned short* __restrict__ TH,
                        const float* __restrict__ b1, const float* __restrict__ b2,
                        const float* __restrict__ b3, const float* __restrict__ b4,
                        const float* __restrict__ BH,
                        const float* __restrict__ dmean, const float* __restrict__ dstd,
                        float* __restrict__ out) {
    __shared__ unsigned short hbuf[TM * HID];   // 64 KB, XOR-swizzled rows
    const int bid = blockIdx.x;
    const int e = bid & 7;                      // ensemble -> XCD affinity
    const int tile = bid >> 3;
    const int row0 = tile * TM;
    const int tid = threadIdx.x, lane = tid & 63, wid = tid >> 6;

    // stage X tile (64 rows x 64 bf16), swizzled
    {
        int r = tid >> 3, c = tid & 7;          // 16B chunk index
        int4 v = *(const int4*)(X + (size_t)(row0 + r) * DINP + c * 8);
        *(int4*)((char*)hbuf + r * 1024 + ((c ^ (r & 7)) << 4)) = v;
    }
    __syncthreads();

    mlp_layer<64,  true>(T1 + (size_t)e * HID * 64,  b1 + e * HID, hbuf, lane, wid);
    mlp_layer<512, true>(T2 + (size_t)e * HID * HID, b2 + e * HID, hbuf, lane, wid);
    mlp_layer<512, true>(T3 + (size_t)e * HID * HID, b3 + e * HID, hbuf, lane, wid);
    mlp_layer<512, true>(T4 + (size_t)e * HID * HID, b4 + e * HID, hbuf, lane, wid);

    // ---- heads: 20 tile-jobs (rt 0..3, ct 0..4) over 8 waves ----
    const int l15 = lane & 15, lk = (lane >> 4) * 8;
    const int j0 = wid, j1 = wid + 8, j2 = wid + 16;
    const bool has2 = (j2 < 20);
    const int rt0 = j0 / 5, ct0 = j0 % 5;
    const int rt1 = j1 / 5, ct1 = j1 % 5;
    const int rt2 = has2 ? j2 / 5 : 0, ct2 = has2 ? j2 % 5 : 0;
    const unsigned short* THe = TH + (size_t)e * NH * HID;
    const float* BHe = BH + e * NH;

    f32x4 h0, h1, h2;
    { float bv = BHe[ct0 * 16 + l15]; h0 = (f32x4){bv, bv, bv, bv}; }
    { float bv = BHe[ct1 * 16 + l15]; h1 = (f32x4){bv, bv, bv, bv}; }
    { float bv = BHe[ct2 * 16 + l15]; h2 = (f32x4){bv, bv, bv, bv}; }

    #pragma unroll
    for (int ks = 0; ks < 16; ++ks) {
        int k = ks * 32 + lk;
        bf16x8 a0 = load_a(hbuf, rt0 * 16 + l15, k);
        bf16x8 w0 = *(const bf16x8*)(THe + (size_t)(ct0 * 16 + l15) * HID + k);
        h0 = __builtin_amdgcn_mfma_f32_16x16x32_bf16(a0, w0, h0, 0, 0, 0);
        bf16x8 a1 = load_a(hbuf, rt1 * 16 + l15, k);
        bf16x8 w1 = *(const bf16x8*)(THe + (size_t)(ct1 * 16 + l15) * HID + k);
        h1 = __builtin_amdgcn_mfma_f32_16x16x32_bf16(a1, w1, h1, 0, 0, 0);
        if (has2) {
            bf16x8 a2 = load_a(hbuf, rt2 * 16 + l15, k);
            bf16x8 w2 = *(const bf16x8*)(THe + (size_t)(ct2 * 16 + l15) * HID + k);
            h2 = __builtin_amdgcn_mfma_f32_16x16x32_bf16(a2, w2, h2, 0, 0, 0);
        }
    }

    // ---- epilogue: clip/exp/denorm, write concatenated fp32 outputs ----
    const size_t STDS_OFF = (size_t)NE * BTOT * OBS;
    const size_t REW_OFF  = 2 * STDS_OFF;
    const size_t DONE_OFF = REW_OFF + (size_t)NE * BTOT;

    auto emit = [&](int rt, int ct, f32x4 v) {
        int col = ct * 16 + l15;
        #pragma unroll
        for (int j = 0; j < 4; ++j) {
            int row = row0 + rt * 16 + (lane >> 4) * 4 + j;
            size_t rb = (size_t)e * BTOT + row;
            float x = v[j];
            if (col < 32) {
                out[rb * 32 + col] = x * dstd[col] + dmean[col];
            } else if (col < 64) {
                int c = col - 32;
                float ls = fminf(fmaxf(x, -10.f), 0.5f);
                out[STDS_OFF + rb * 32 + c] = expf(ls) * dstd[c];
            } else if (col == 64) {
                out[REW_OFF + rb] = x;
            } else if (col == 65) {
                out[DONE_OFF + rb] = x;
            }
        }
    };
    emit(rt0, ct0, h0);
    emit(rt1, ct1, h1);
    if (has2) emit(rt2, ct2, h2);
}

// ---------------- launch ----------------

extern "C" void kernel_launch(void* const* d_in, const int* in_sizes, int n_in,
                              void* d_out, int out_size, void* d_ws, size_t ws_size,
                              hipStream_t stream) {
    const float* states  = (const float*)d_in[0];
    const float* actions = (const float*)d_in[1];
    const float* smean   = (const float*)d_in[2];
    const float* sstd    = (const float*)d_in[3];
    const float* amean   = (const float*)d_in[4];
    const float* astd    = (const float*)d_in[5];
    const float* dmean   = (const float*)d_in[6];
    const float* dstd    = (const float*)d_in[7];
    const float* W1 = (const float*)d_in[8];
    const float* b1 = (const float*)d_in[9];
    const float* W2 = (const float*)d_in[10];
    const float* b2 = (const float*)d_in[11];
    const float* W3 = (const float*)d_in[12];
    const float* b3 = (const float*)d_in[13];
    const float* W4 = (const float*)d_in[14];
    const float* b4 = (const float*)d_in[15];
    const float* Wm = (const float*)d_in[16];
    const float* bm = (const float*)d_in[17];
    const float* Wls = (const float*)d_in[18];
    const float* bls = (const float*)d_in[19];
    const float* Wr = (const float*)d_in[20];
    const float* br = (const float*)d_in[21];
    const float* Wd = (const float*)d_in[22];
    const float* bd = (const float*)d_in[23];

    char* ws = (char*)d_ws;
    unsigned short* X  = (unsigned short*)(ws);                 // 4,194,304 B
    unsigned short* T1 = (unsigned short*)(ws + 4194304);       //   524,288 B
    unsigned short* T2 = (unsigned short*)(ws + 4718592);       // 4,194,304 B
    unsigned short* T3 = (unsigned short*)(ws + 8912896);
    unsigned short* T4 = (unsigned short*)(ws + 13107200);
    unsigned short* TH = (unsigned short*)(ws + 17301504);      //   655,360 B
    float*          BH = (float*)(ws + 17956864);               //     2,560 B

    prep_x<<<(BTOT * 64) / 256, 256, 0, stream>>>(states, actions, smean, sstd, amean, astd, X);
    prep_w1<<<(NE * HID * 64) / 256, 256, 0, stream>>>(W1, T1);
    dim3 gT(16, 16, 24), bT(32, 8);
    prep_wh<<<gT, bT, 0, stream>>>(W2, W3, W4, T2);
    prep_head<<<(NE * NH * HID) / 256, 256, 0, stream>>>(Wm, Wls, Wr, Wd, bm, bls, br, bd, TH, BH);

    ens_mlp<<<NE * (BTOT / TM), 512, 0, stream>>>(X, T1, T2, T3, T4, TH,
                                                  b1, b2, b3, b4, BH, dmean, dstd,
                                                  (float*)d_out);
}

// Round 7
// 1111.173 us; speedup vs baseline: 1.6212x; 1.0103x over previous
//
#include <hip/hip_runtime.h>
#include <hip/hip_bf16.h>
#include <stdint.h>

#define NE 8
#define HID 512
#define OBS 32
#define ACT 16
#define DIN 48
#define DINP 64     // padded input dim
#define BTOT 32768
#define TM 64       // rows per block
#define NH 80       // padded head outputs (66 -> 80)

typedef short bf16x8 __attribute__((ext_vector_type(8)));
typedef float f32x4 __attribute__((ext_vector_type(4)));

__device__ __forceinline__ unsigned short f2bf(float f) {
    union { float f; unsigned u; } v; v.f = f;
    unsigned u = v.u + 0x7FFF + ((v.u >> 16) & 1);
    return (unsigned short)(u >> 16);
}

// ---------------- prep kernels ----------------

// X[b][c] = normalized concat(states, actions), zero-padded to 64, bf16
__global__ void prep_x(const float* __restrict__ st, const float* __restrict__ ac,
                       const float* __restrict__ sm, const float* __restrict__ ss,
                       const float* __restrict__ am, const float* __restrict__ as_,
                       unsigned short* __restrict__ X) {
    int idx = blockIdx.x * 256 + threadIdx.x;   // B*64 total
    int b = idx >> 6, c = idx & 63;
    float v = 0.f;
    if (c < OBS) v = (st[b * OBS + c] - sm[c]) / ss[c];
    else if (c < DIN) { int ca = c - OBS; v = (ac[b * ACT + ca] - am[ca]) / as_[ca]; }
    X[idx] = f2bf(v);
}

// T1[e][n][k] = W1[e][k][n] (k<48 else 0), bf16, K padded to 64
__global__ void prep_w1(const float* __restrict__ W1, unsigned short* __restrict__ T1) {
    int idx = blockIdx.x * 256 + threadIdx.x;   // 8*512*64
    int k = idx & 63, n = (idx >> 6) & 511, e = idx >> 15;
    float v = (k < DIN) ? W1[((size_t)e * DIN + k) * HID + n] : 0.f;
    T1[idx] = f2bf(v);
}

// Transposed bf16 copies of W2/W3/W4: T[z][n][k] = Wsrc[e][k][n], z = l*8+e
__global__ void prep_wh(const float* __restrict__ W2, const float* __restrict__ W3,
                        const float* __restrict__ W4, unsigned short* __restrict__ T) {
    __shared__ float tile[32][33];
    int z = blockIdx.z;
    const float* src = (z < 8 ? W2 : (z < 16 ? W3 : W4)) + (size_t)(z & 7) * HID * HID;
    unsigned short* dst = T + (size_t)z * HID * HID;
    int n0 = blockIdx.x * 32, k0 = blockIdx.y * 32;
    int tx = threadIdx.x, ty = threadIdx.y;     // 32 x 8
    #pragma unroll
    for (int i = 0; i < 32; i += 8)
        tile[ty + i][tx] = src[(size_t)(k0 + ty + i) * HID + n0 + tx];
    __syncthreads();
    #pragma unroll
    for (int i = 0; i < 32; i += 8)
        dst[(size_t)(n0 + ty + i) * HID + k0 + tx] = f2bf(tile[tx][ty + i]);
}

// Fused head weights TH[e][n][k] (n<32 means, <64 logstd, 64 reward, 65 done, rest 0)
// and fused head bias BH[e][n]
__global__ void prep_head(const float* __restrict__ Wm, const float* __restrict__ Wls,
                          const float* __restrict__ Wr, const float* __restrict__ Wd,
                          const float* __restrict__ bm, const float* __restrict__ bls,
                          const float* __restrict__ br, const float* __restrict__ bd,
                          unsigned short* __restrict__ TH, float* __restrict__ BH) {
    int idx = blockIdx.x * 256 + threadIdx.x;   // 8*80*512
    if (idx < NE * NH * HID) {
        int k = idx & 511, n = (idx >> 9) % NH, e = idx / (NH * HID);
        float v = 0.f;
        if (n < 32)       v = Wm [((size_t)e * HID + k) * OBS + n];
        else if (n < 64)  v = Wls[((size_t)e * HID + k) * OBS + (n - 32)];
        else if (n == 64) v = Wr [(size_t)e * HID + k];
        else if (n == 65) v = Wd [(size_t)e * HID + k];
        TH[idx] = f2bf(v);
    }
    if (idx < NE * NH) {
        int n = idx % NH, e = idx / NH;
        float v = 0.f;
        if (n < 32)       v = bm [e * OBS + n];
        else if (n < 64)  v = bls[e * OBS + (n - 32)];
        else if (n == 64) v = br [e];
        else if (n == 65) v = bd [e];
        BH[idx] = v;
    }
}

// ---------------- main fused kernel ----------------

__device__ __forceinline__ bf16x8 load_a(const unsigned short* hb, int row, int k) {
    int off = row * 1024 + ((k * 2) ^ ((row & 7) << 4));
    return *(const bf16x8*)((const char*)hb + off);
}

// 16 waves; each wave owns ALL 64 rows x 32 cols (cols = wid*32 .. +31).
// 2 B-frag loads per 8 MFMAs, no intra-block B redundancy; B-only depth-1
// register double buffer (round-4-proven structure). Latency hiding comes
// from 4 waves/SIMD TLP.
template<int KD, bool RELU>
__device__ __forceinline__ void mlp_layer(const unsigned short* __restrict__ Tw,
                                          const float* __restrict__ bias,
                                          unsigned short* __restrict__ hb,
                                          int lane, int wid) {
    const int l15 = lane & 15, lk = (lane >> 4) * 8;
    const int col0 = wid * 32;
    constexpr int NK = KD / 32;

    f32x4 acc[4][2];
    #pragma unroll
    for (int ct = 0; ct < 2; ++ct) {
        float bv = bias[col0 + ct * 16 + l15];
        f32x4 b4 = {bv, bv, bv, bv};
        #pragma unroll
        for (int rt = 0; rt < 4; ++rt) acc[rt][ct] = b4;
    }

    // B row base for this lane: row (col0 + ct*16 + l15), k = ks*32 + lk
    const unsigned short* Bb = Tw + (size_t)(col0 + l15) * KD + lk;

    bf16x8 bcur[2], bnxt[2];
    #pragma unroll
    for (int ct = 0; ct < 2; ++ct)
        bcur[ct] = *(const bf16x8*)(Bb + ct * 16 * KD);

    #pragma unroll
    for (int ks = 0; ks < NK; ++ks) {
        const int k = ks * 32 + lk;
        if (ks + 1 < NK) {
            #pragma unroll
            for (int ct = 0; ct < 2; ++ct)
                bnxt[ct] = *(const bf16x8*)(Bb + ct * 16 * KD + (ks + 1) * 32);
        }
        bf16x8 a0 = load_a(hb, 0 * 16 + l15, k);
        bf16x8 a1 = load_a(hb, 1 * 16 + l15, k);
        #pragma unroll
        for (int ct = 0; ct < 2; ++ct) {
            acc[0][ct] = __builtin_amdgcn_mfma_f32_16x16x32_bf16(a0, bcur[ct], acc[0][ct], 0, 0, 0);
            acc[1][ct] = __builtin_amdgcn_mfma_f32_16x16x32_bf16(a1, bcur[ct], acc[1][ct], 0, 0, 0);
        }
        bf16x8 a2 = load_a(hb, 2 * 16 + l15, k);
        bf16x8 a3 = load_a(hb, 3 * 16 + l15, k);
        #pragma unroll
        for (int ct = 0; ct < 2; ++ct) {
            acc[2][ct] = __builtin_amdgcn_mfma_f32_16x16x32_bf16(a2, bcur[ct], acc[2][ct], 0, 0, 0);
            acc[3][ct] = __builtin_amdgcn_mfma_f32_16x16x32_bf16(a3, bcur[ct], acc[3][ct], 0, 0, 0);
        }
        if (ks + 1 < NK) {
            #pragma unroll
            for (int ct = 0; ct < 2; ++ct) bcur[ct] = bnxt[ct];
        }
    }
    __syncthreads();
    #pragma unroll
    for (int rt = 0; rt < 4; ++rt)
        #pragma unroll
        for (int ct = 0; ct < 2; ++ct)
            #pragma unroll
            for (int j = 0; j < 4; ++j) {
                int row = rt * 16 + (lane >> 4) * 4 + j;
                int col = col0 + ct * 16 + l15;
                float v = acc[rt][ct][j];
                if (RELU) v = fmaxf(v, 0.f);
                *(unsigned short*)((char*)hb + row * 1024 + ((col * 2) ^ ((row & 7) << 4))) = f2bf(v);
            }
    __syncthreads();
}

__launch_bounds__(1024, 4)
__global__ void ens_mlp(const unsigned short* __restrict__ X,
                        const unsigned short* __restrict__ T1, const unsigned short* __restrict__ T2,
                        const unsigned short* __restrict__ T3, const unsigned short* __restrict__ T4,
                        const unsigned short* __restrict__ TH,
                        const float* __restrict__ b1, const float* __restrict__ b2,
                        const float* __restrict__ b3, const float* __restrict__ b4,
                        const float* __restrict__ BH,
                        const float* __restrict__ dmean, const float* __restrict__ dstd,
                        float* __restrict__ out) {
    __shared__ unsigned short hbuf[TM * HID];   // 64 KB, XOR-swizzled rows
    const int bid = blockIdx.x;
    const int e = bid & 7;                      // ensemble -> XCD affinity
    const int tile = bid >> 3;
    const int row0 = tile * TM;
    const int tid = threadIdx.x, lane = tid & 63, wid = tid >> 6;

    // stage X tile (64 rows x 64 bf16), swizzled; 512 chunks over 1024 threads
    if (tid < 512) {
        int r = tid >> 3, c = tid & 7;          // 16B chunk index
        int4 v = *(const int4*)(X + (size_t)(row0 + r) * DINP + c * 8);
        *(int4*)((char*)hbuf + r * 1024 + ((c ^ (r & 7)) << 4)) = v;
    }
    __syncthreads();

    mlp_layer<64,  true>(T1 + (size_t)e * HID * 64,  b1 + e * HID, hbuf, lane, wid);
    mlp_layer<512, true>(T2 + (size_t)e * HID * HID, b2 + e * HID, hbuf, lane, wid);
    mlp_layer<512, true>(T3 + (size_t)e * HID * HID, b3 + e * HID, hbuf, lane, wid);
    mlp_layer<512, true>(T4 + (size_t)e * HID * HID, b4 + e * HID, hbuf, lane, wid);

    // ---- heads: 20 tile-jobs (rt 0..3, ct 0..4) over 16 waves ----
    const int l15 = lane & 15, lk = (lane >> 4) * 8;
    const int j0 = wid, j1 = wid + 16;
    const bool has1 = (j1 < 20);
    const int rt0 = j0 / 5, ct0 = j0 % 5;
    const int rt1 = has1 ? j1 / 5 : 0, ct1 = has1 ? j1 % 5 : 0;
    const unsigned short* THe = TH + (size_t)e * NH * HID;
    const float* BHe = BH + e * NH;

    f32x4 h0, h1;
    { float bv = BHe[ct0 * 16 + l15]; h0 = (f32x4){bv, bv, bv, bv}; }
    { float bv = BHe[ct1 * 16 + l15]; h1 = (f32x4){bv, bv, bv, bv}; }

    #pragma unroll
    for (int ks = 0; ks < 16; ++ks) {
        int k = ks * 32 + lk;
        bf16x8 a0 = load_a(hbuf, rt0 * 16 + l15, k);
        bf16x8 w0 = *(const bf16x8*)(THe + (size_t)(ct0 * 16 + l15) * HID + k);
        h0 = __builtin_amdgcn_mfma_f32_16x16x32_bf16(a0, w0, h0, 0, 0, 0);
        if (has1) {
            bf16x8 a1 = load_a(hbuf, rt1 * 16 + l15, k);
            bf16x8 w1 = *(const bf16x8*)(THe + (size_t)(ct1 * 16 + l15) * HID + k);
            h1 = __builtin_amdgcn_mfma_f32_16x16x32_bf16(a1, w1, h1, 0, 0, 0);
        }
    }

    // ---- epilogue: clip/exp/denorm, write concatenated fp32 outputs ----
    const size_t STDS_OFF = (size_t)NE * BTOT * OBS;
    const size_t REW_OFF  = 2 * STDS_OFF;
    const size_t DONE_OFF = REW_OFF + (size_t)NE * BTOT;

    auto emit = [&](int rt, int ct, f32x4 v) {
        int col = ct * 16 + l15;
        #pragma unroll
        for (int j = 0; j < 4; ++j) {
            int row = row0 + rt * 16 + (lane >> 4) * 4 + j;
            size_t rb = (size_t)e * BTOT + row;
            float x = v[j];
            if (col < 32) {
                out[rb * 32 + col] = x * dstd[col] + dmean[col];
            } else if (col < 64) {
                int c = col - 32;
                float ls = fminf(fmaxf(x, -10.f), 0.5f);
                out[STDS_OFF + rb * 32 + c] = expf(ls) * dstd[c];
            } else if (col == 64) {
                out[REW_OFF + rb] = x;
            } else if (col == 65) {
                out[DONE_OFF + rb] = x;
            }
        }
    };
    emit(rt0, ct0, h0);
    if (has1) emit(rt1, ct1, h1);
}

// ---------------- launch ----------------

extern "C" void kernel_launch(void* const* d_in, const int* in_sizes, int n_in,
                              void* d_out, int out_size, void* d_ws, size_t ws_size,
                              hipStream_t stream) {
    const float* states  = (const float*)d_in[0];
    const float* actions = (const float*)d_in[1];
    const float* smean   = (const float*)d_in[2];
    const float* sstd    = (const float*)d_in[3];
    const float* amean   = (const float*)d_in[4];
    const float* astd    = (const float*)d_in[5];
    const float* dmean   = (const float*)d_in[6];
    const float* dstd    = (const float*)d_in[7];
    const float* W1 = (const float*)d_in[8];
    const float* b1 = (const float*)d_in[9];
    const float* W2 = (const float*)d_in[10];
    const float* b2 = (const float*)d_in[11];
    const float* W3 = (const float*)d_in[12];
    const float* b3 = (const float*)d_in[13];
    const float* W4 = (const float*)d_in[14];
    const float* b4 = (const float*)d_in[15];
    const float* Wm = (const float*)d_in[16];
    const float* bm = (const float*)d_in[17];
    const float* Wls = (const float*)d_in[18];
    const float* bls = (const float*)d_in[19];
    const float* Wr = (const float*)d_in[20];
    const float* br = (const float*)d_in[21];
    const float* Wd = (const float*)d_in[22];
    const float* bd = (const float*)d_in[23];

    char* ws = (char*)d_ws;
    unsigned short* X  = (unsigned short*)(ws);                 // 4,194,304 B
    unsigned short* T1 = (unsigned short*)(ws + 4194304);       //   524,288 B
    unsigned short* T2 = (unsigned short*)(ws + 4718592);       // 4,194,304 B
    unsigned short* T3 = (unsigned short*)(ws + 8912896);
    unsigned short* T4 = (unsigned short*)(ws + 13107200);
    unsigned short* TH = (unsigned short*)(ws + 17301504);      //   655,360 B
    float*          BH = (float*)(ws + 17956864);               //     2,560 B

    prep_x<<<(BTOT * 64) / 256, 256, 0, stream>>>(states, actions, smean, sstd, amean, astd, X);
    prep_w1<<<(NE * HID * 64) / 256, 256, 0, stream>>>(W1, T1);
    dim3 gT(16, 16, 24), bT(32, 8);
    prep_wh<<<gT, bT, 0, stream>>>(W2, W3, W4, T2);
    prep_head<<<(NE * NH * HID) / 256, 256, 0, stream>>>(Wm, Wls, Wr, Wd, bm, bls, br, bd, TH, BH);

    ens_mlp<<<NE * (BTOT / TM), 1024, 0, stream>>>(X, T1, T2, T3, T4, TH,
                                                   b1, b2, b3, b4, BH, dmean, dstd,
                                                   (float*)d_out);
}